// Round 8
// baseline (398.404 us; speedup 1.0000x reference)
//
#include <hip/hip_runtime.h>
#include <stdint.h>

#define HW   4096
#define CIN  512

typedef __attribute__((ext_vector_type(8))) short short8;
typedef __attribute__((ext_vector_type(4))) float f32x4;
typedef unsigned short u16;

#define GL16(src, ldsdst) __builtin_amdgcn_global_load_lds(                    \
    (const __attribute__((address_space(1))) void*)(src),                      \
    (__attribute__((address_space(3))) void*)(ldsdst), 16, 0, 0)

__device__ __forceinline__ u16 f2bf(float f) {
  union { float f; uint32_t u; } c; c.f = f;
  uint32_t r = (c.u + 0x7FFFu + ((c.u >> 16) & 1u)) >> 16;
  return (u16)r;
}
__device__ __forceinline__ float bf2f(u16 h) {
  union { uint32_t u; float f; } c; c.u = ((uint32_t)h) << 16;
  return c.f;
}

// ---------------------------------------------------------------------------
// x (B,C,HW) fp32  ->  xbT (B*HW, C) bf16   (64x64 tile transpose via LDS)
// ---------------------------------------------------------------------------
__global__ __launch_bounds__(256) void cast_xT(const float* __restrict__ x,
                                               u16* __restrict__ xbT) {
  __shared__ u16 t[64 * 72];
  int p0 = blockIdx.x * 64, c0 = blockIdx.y * 64, b = blockIdx.z;
  int tid = threadIdx.x, r = tid >> 2, ch = tid & 3;
  const float* xp = x + ((size_t)b * CIN + c0 + r) * HW + p0 + ch * 16;
  float4 f0 = *(const float4*)(xp + 0);
  float4 f1 = *(const float4*)(xp + 4);
  float4 f2 = *(const float4*)(xp + 8);
  float4 f3 = *(const float4*)(xp + 12);
  u16* tr = &t[r * 72 + ch * 16];
  tr[0] = f2bf(f0.x); tr[1] = f2bf(f0.y); tr[2] = f2bf(f0.z); tr[3] = f2bf(f0.w);
  tr[4] = f2bf(f1.x); tr[5] = f2bf(f1.y); tr[6] = f2bf(f1.z); tr[7] = f2bf(f1.w);
  tr[8] = f2bf(f2.x); tr[9] = f2bf(f2.y); tr[10] = f2bf(f2.z); tr[11] = f2bf(f2.w);
  tr[12] = f2bf(f3.x); tr[13] = f2bf(f3.y); tr[14] = f2bf(f3.z); tr[15] = f2bf(f3.w);
  __syncthreads();
  u16 o[16];
#pragma unroll
  for (int j = 0; j < 16; j++) o[j] = t[(ch * 16 + j) * 72 + r];
  u16* op = xbT + ((size_t)b * HW + p0 + r) * CIN + c0 + ch * 16;
  *(short8*)(op) = *(short8*)&o[0];
  *(short8*)(op + 8) = *(short8*)&o[8];
}

// ---------------------------------------------------------------------------
// weights -> bf16; wqk = [Wq*log2e; Wk] (128,512); bqk = [bq*log2e; bk]
// ---------------------------------------------------------------------------
__global__ void cast_w(const float* __restrict__ Wq, const float* __restrict__ Wk,
                       const float* __restrict__ Wv, const float* __restrict__ Wd,
                       const float* __restrict__ bq, const float* __restrict__ bk,
                       u16* __restrict__ wqk, u16* __restrict__ wv,
                       u16* __restrict__ wd, float* __restrict__ bqk) {
  const float LOG2E = 1.4426950408889634f;
  int i = blockIdx.x * 256 + threadIdx.x;
  if (i < 65536) wqk[i] = f2bf(i < 32768 ? Wq[i] * LOG2E : Wk[i - 32768]);
  if (i < 262144) { wv[i] = f2bf(Wv[i]); wd[i] = f2bf(Wd[i]); }
  if (i < 128) bqk[i] = (i < 64) ? bq[i] * LOG2E : bk[i - 64];
}

// ---------------------------------------------------------------------------
// Generic GEMM: C(M,N) = A(M,K) * BT(N,K)^T  (both bf16, K-contiguous rows)
// m97-style: 128x128 tile, BK=32, global_load_lds(16B) staging, 4 waves.
// mode 0: out row-major (M,N) bf16, bias[col]
// mode 1: out (B, M, HW) bf16, col=b*HW+p, bias[row]
// mode 2: out (B, M, HW) fp32, bias[row]
// ---------------------------------------------------------------------------
__global__ __launch_bounds__(256) void gemm_bf16(
    const u16* __restrict__ A, const u16* __restrict__ BT,
    const float* __restrict__ bias, void* __restrict__ out,
    int M, int N, int K, int mode) {
  __shared__ u16 la[128 * 32];
  __shared__ u16 lb[128 * 32];
  int tid = threadIdx.x;
  int w = tid >> 6, lane = tid & 63, m = lane & 15, g = lane >> 4;
  int wm = w >> 1, wn = w & 1;
  int m0 = blockIdx.y * 128, n0 = blockIdx.x * 128;
  int sr = lane >> 2, sc = (lane & 3) * 8;
  const u16* pa0 = A + (size_t)(m0 + w * 32 + sr) * K + sc;
  const u16* pa1 = pa0 + (size_t)16 * K;
  const u16* pb0 = BT + (size_t)(n0 + w * 32 + sr) * K + sc;
  const u16* pb1 = pb0 + (size_t)16 * K;
  u16* la0 = &la[(w * 32) * 32];
  u16* la1 = &la[(w * 32 + 16) * 32];
  u16* lb0 = &lb[(w * 32) * 32];
  u16* lb1 = &lb[(w * 32 + 16) * 32];

  f32x4 acc[4][4];
  f32x4 zero = {0.f, 0.f, 0.f, 0.f};
#pragma unroll
  for (int i = 0; i < 4; i++)
#pragma unroll
    for (int j = 0; j < 4; j++) acc[i][j] = zero;

  for (int k0 = 0; k0 < K; k0 += 32) {
    __syncthreads();
    GL16(pa0 + k0, la0);
    GL16(pa1 + k0, la1);
    GL16(pb0 + k0, lb0);
    GL16(pb1 + k0, lb1);
    __syncthreads();
    short8 af[4], bf[4];
#pragma unroll
    for (int i = 0; i < 4; i++)
      af[i] = *(const short8*)&la[(wm * 64 + i * 16 + m) * 32 + g * 8];
#pragma unroll
    for (int j = 0; j < 4; j++)
      bf[j] = *(const short8*)&lb[(wn * 64 + j * 16 + m) * 32 + g * 8];
#pragma unroll
    for (int i = 0; i < 4; i++)
#pragma unroll
      for (int j = 0; j < 4; j++)
        acc[i][j] = __builtin_amdgcn_mfma_f32_16x16x32_bf16(af[i], bf[j], acc[i][j], 0, 0, 0);
  }

#pragma unroll
  for (int i = 0; i < 4; i++) {
#pragma unroll
    for (int j = 0; j < 4; j++) {
      int row_l = m0 + wm * 64 + i * 16 + g * 4;
      int col = n0 + wn * 64 + j * 16 + m;
#pragma unroll
      for (int r = 0; r < 4; r++) {
        int row = row_l + r;
        float v = acc[i][j][r];
        if (mode == 0) {
          v += bias[col];
          ((u16*)out)[(size_t)row * N + col] = f2bf(v);
        } else {
          v += bias[row];
          size_t addr = ((size_t)(col >> 12) * M + row) * HW + (col & (HW - 1));
          if (mode == 1) ((u16*)out)[addr] = f2bf(v);
          else           ((float*)out)[addr] = v;
        }
      }
    }
  }
}

// ---------------------------------------------------------------------------
// ppass: P = exp2(Q K^T) materialized bf16 + exact row-sum reciprocals.
// LDS-free: K fragments read directly from global (L2-resident, 512 KB/batch).
// Grid: nb*64 blocks (64 q-rows each), 512 thr / 8 waves, no loop barriers.
// Wave (qg=w&3, jh=w>>2): 16 q-rows x contiguous 2048-j half.
// ---------------------------------------------------------------------------
__global__ __launch_bounds__(512) void ppass(
    const u16* __restrict__ qkT, u16* __restrict__ P,
    float* __restrict__ li, int b0) {
  __shared__ float red[2][64];
  int tid = threadIdx.x;
  int w = tid >> 6, lane = tid & 63, m = lane & 15, g = lane >> 4;
  int blk = blockIdx.x;
  int bb = blk >> 6, b = b0 + bb;
  int q0 = (blk & 63) << 6;
  int qg = w & 3, jh = w >> 2;
  size_t qrow = (size_t)b * HW + q0;

  short8 aq[2];
#pragma unroll
  for (int ks = 0; ks < 2; ks++)
    aq[ks] = *(const short8*)(qkT + (qrow + qg * 16 + m) * 128 + ks * 32 + g * 8);

  float lr[4] = {0.f, 0.f, 0.f, 0.f};
  u16* Pb = P + ((size_t)bb * HW + q0) * HW;
  const u16* kb = qkT + (size_t)b * HW * 128 + 64;
  f32x4 zero = {0.f, 0.f, 0.f, 0.f};

#pragma unroll 4
  for (int js = 0; js < 128; js++) {
    int jr = jh * 2048 + js * 16;
    const u16* kr = kb + (size_t)(jr + m) * 128;
    f32x4 s = zero;
#pragma unroll
    for (int ks = 0; ks < 2; ks++) {
      short8 bk = *(const short8*)(kr + ks * 32 + g * 8);
      s = __builtin_amdgcn_mfma_f32_16x16x32_bf16(aq[ks], bk, s, 0, 0, 0);
    }
#pragma unroll
    for (int r = 0; r < 4; r++) {
      float p = exp2f(s[r]);
      lr[r] += p;
      Pb[(size_t)(qg * 16 + g * 4 + r) * HW + jr + m] = f2bf(p);
    }
  }
  // exact row sums: reduce over 16 key-lanes, then across jh halves
#pragma unroll
  for (int r = 0; r < 4; r++) {
#pragma unroll
    for (int off = 1; off < 16; off <<= 1)
      lr[r] += __shfl_xor(lr[r], off);
  }
  __syncthreads();
  if (m == 0) {
#pragma unroll
    for (int r = 0; r < 4; r++) red[jh][qg * 16 + g * 4 + r] = lr[r];
  }
  __syncthreads();
  if (tid < 64) li[qrow + tid] = 1.0f / (red[0][tid] + red[1][tid]);
}

// ---------------------------------------------------------------------------
// gemm_pv: uT = gamma * (P * V^T) .* li + xbT.
// LDS-FREE streaming GEMM: 128q x 256c tile, 8 waves (2M x 4N), 64x64/wave.
// Fragments loaded direct from global (P streamed / L3, V L2-resident),
// depth-4 software pipeline (named buffers, static indexing), no barriers.
// Grid (2, 32, nb), 512 thr.
// ---------------------------------------------------------------------------
__global__ __launch_bounds__(512) void gemm_pv(
    const u16* __restrict__ P, const u16* __restrict__ V,
    const float* __restrict__ li, const u16* __restrict__ xbT,
    const float* __restrict__ gamma, u16* __restrict__ uT, int b0) {
  int tid = threadIdx.x;
  int w = tid >> 6, lane = tid & 63, m = lane & 15, g = lane >> 4;
  int wm = w >> 2, wn = w & 3;
  int bb = blockIdx.z, b = b0 + bb;
  int n0 = blockIdx.x * 256;
  int m0 = blockIdx.y * 128;
  const u16* pa  = P + ((size_t)bb * HW + m0 + wm * 64 + m) * HW + g * 8;
  const u16* pbv = V + ((size_t)b * CIN + n0 + wn * 64 + m) * HW + g * 8;

  f32x4 acc[4][4];
  f32x4 zero = {0.f, 0.f, 0.f, 0.f};
#pragma unroll
  for (int i = 0; i < 4; i++)
#pragma unroll
    for (int j = 0; j < 4; j++) acc[i][j] = zero;

#define LDSTEP(af, bf, kk)                                                     \
  do {                                                                         \
    _Pragma("unroll")                                                          \
    for (int i = 0; i < 4; i++)                                                \
      af[i] = *(const short8*)(pa + (size_t)(i * 16) * HW + (kk));             \
    _Pragma("unroll")                                                          \
    for (int j = 0; j < 4; j++)                                                \
      bf[j] = *(const short8*)(pbv + (size_t)(j * 16) * HW + (kk));            \
  } while (0)

#define MMSTEP(af, bf)                                                         \
  do {                                                                         \
    _Pragma("unroll")                                                          \
    for (int i = 0; i < 4; i++)                                                \
      _Pragma("unroll")                                                        \
      for (int j = 0; j < 4; j++)                                              \
        acc[i][j] = __builtin_amdgcn_mfma_f32_16x16x32_bf16(af[i], bf[j],      \
                                                            acc[i][j], 0, 0, 0); \
  } while (0)

  short8 a0[4], b0f[4], a1[4], b1f[4], a2[4], b2f[4], a3[4], b3f[4];
  LDSTEP(a0, b0f, 0);
  LDSTEP(a1, b1f, 32);
  LDSTEP(a2, b2f, 64);
  LDSTEP(a3, b3f, 96);
  for (int k0 = 128; k0 < HW; k0 += 128) {
    MMSTEP(a0, b0f); LDSTEP(a0, b0f, k0);
    MMSTEP(a1, b1f); LDSTEP(a1, b1f, k0 + 32);
    MMSTEP(a2, b2f); LDSTEP(a2, b2f, k0 + 64);
    MMSTEP(a3, b3f); LDSTEP(a3, b3f, k0 + 96);
  }
  MMSTEP(a0, b0f);
  MMSTEP(a1, b1f);
  MMSTEP(a2, b2f);
  MMSTEP(a3, b3f);
#undef LDSTEP
#undef MMSTEP

  float gm = gamma[0];
#pragma unroll
  for (int i = 0; i < 4; i++) {
#pragma unroll
    for (int j = 0; j < 4; j++) {
#pragma unroll
      for (int r = 0; r < 4; r++) {
        int q = m0 + wm * 64 + i * 16 + g * 4 + r;
        int c = n0 + wn * 64 + j * 16 + m;
        size_t row = (size_t)b * HW + q;
        float o = acc[i][j][r] * li[row];
        float xv = bf2f(xbT[row * CIN + c]);
        uT[row * CIN + c] = f2bf(gm * o + xv);
      }
    }
  }
}

// ---------------------------------------------------------------------------
extern "C" void kernel_launch(void* const* d_in, const int* in_sizes, int n_in,
                              void* d_out, int out_size, void* d_ws, size_t ws_size,
                              hipStream_t stream) {
  const float* x     = (const float*)d_in[0];
  const float* Wq    = (const float*)d_in[1];
  const float* bq    = (const float*)d_in[2];
  const float* Wk    = (const float*)d_in[3];
  const float* bk    = (const float*)d_in[4];
  const float* Wv    = (const float*)d_in[5];
  const float* bv    = (const float*)d_in[6];
  const float* gamma = (const float*)d_in[7];
  const float* Wd    = (const float*)d_in[8];
  const float* bd    = (const float*)d_in[9];

  char* ws = (char*)d_ws;
  size_t off = 0;
  auto alloc = [&](size_t bytes) {
    void* p = ws + off;
    off += (bytes + 255) & ~(size_t)255;
    return p;
  };
  u16*   xbT = (u16*)alloc((size_t)16384 * 512 * 2);
  u16*   qkT = (u16*)alloc((size_t)16384 * 128 * 2);
  u16*   vb  = (u16*)alloc((size_t)16384 * 512 * 2);
  u16*   uT  = (u16*)alloc((size_t)16384 * 512 * 2);
  u16*   wqk = (u16*)alloc((size_t)65536 * 2);
  u16*   wvb = (u16*)alloc((size_t)262144 * 2);
  u16*   wdb = (u16*)alloc((size_t)262144 * 2);
  float* bqk = (float*)alloc(128 * 4);
  float* li  = (float*)alloc((size_t)16384 * 4);
  size_t PB = (size_t)HW * HW * 2;
  int nb = 0;
  if      (off + 4 * PB <= ws_size) nb = 4;
  else if (off + 2 * PB <= ws_size) nb = 2;
  else if (off + 1 * PB <= ws_size) nb = 1;
  if (nb == 0) return;  // workspace too small -> poison stays -> loud failure
  u16* Pbuf = (u16*)alloc(nb * PB);

  cast_xT<<<dim3(64, 8, 4), 256, 0, stream>>>(x, xbT);
  cast_w<<<1024, 256, 0, stream>>>(Wq, Wk, Wv, Wd, bq, bk, wqk, wvb, wdb, bqk);
  // qkT (16384,128) = xbT * wqk^T
  gemm_bf16<<<dim3(1, 128), 256, 0, stream>>>(xbT, wqk, bqk, qkT, 16384, 128, 512, 0);
  // v (B,512,HW) = Wv * x
  gemm_bf16<<<dim3(128, 4), 256, 0, stream>>>(wvb, xbT, bv, vb, 512, 16384, 512, 1);
  // attention: P materialize + PV GEMM (staged by batch groups of nb)
  for (int b0 = 0; b0 < 4; b0 += nb) {
    ppass<<<dim3(nb * 64), 512, 0, stream>>>(qkT, Pbuf, li, b0);
    gemm_pv<<<dim3(2, 32, nb), 512, 0, stream>>>(Pbuf, vb, li, xbT, gamma, uT, b0);
  }
  // pam_out (B,512,HW) fp32 = Wd * u
  gemm_bf16<<<dim3(128, 4), 256, 0, stream>>>(wdb, uT, bd, d_out, 512, 16384, 512, 2);
}

// Round 10
// 234.153 us; speedup vs baseline: 1.7015x; 1.7015x over previous
//
#include <hip/hip_runtime.h>
#include <stdint.h>

#define HW   4096
#define CIN  512

typedef __attribute__((ext_vector_type(8))) short short8;
typedef __attribute__((ext_vector_type(4))) float f32x4;
typedef unsigned short u16;

#define GL16(src, ldsdst) __builtin_amdgcn_global_load_lds(                    \
    (const __attribute__((address_space(1))) void*)(src),                      \
    (__attribute__((address_space(3))) void*)(ldsdst), 16, 0, 0)

__device__ __forceinline__ u16 f2bf(float f) {
  union { float f; uint32_t u; } c; c.f = f;
  uint32_t r = (c.u + 0x7FFFu + ((c.u >> 16) & 1u)) >> 16;
  return (u16)r;
}
__device__ __forceinline__ float bf2f(u16 h) {
  union { uint32_t u; float f; } c; c.u = ((uint32_t)h) << 16;
  return c.f;
}

// ---------------------------------------------------------------------------
// x (B,C,HW) fp32  ->  xbT (B*HW, C) bf16   (64x64 tile transpose via LDS)
// ---------------------------------------------------------------------------
__global__ __launch_bounds__(256) void cast_xT(const float* __restrict__ x,
                                               u16* __restrict__ xbT) {
  __shared__ u16 t[64 * 72];
  int p0 = blockIdx.x * 64, c0 = blockIdx.y * 64, b = blockIdx.z;
  int tid = threadIdx.x, r = tid >> 2, ch = tid & 3;
  const float* xp = x + ((size_t)b * CIN + c0 + r) * HW + p0 + ch * 16;
  float4 f0 = *(const float4*)(xp + 0);
  float4 f1 = *(const float4*)(xp + 4);
  float4 f2 = *(const float4*)(xp + 8);
  float4 f3 = *(const float4*)(xp + 12);
  u16* tr = &t[r * 72 + ch * 16];
  tr[0] = f2bf(f0.x); tr[1] = f2bf(f0.y); tr[2] = f2bf(f0.z); tr[3] = f2bf(f0.w);
  tr[4] = f2bf(f1.x); tr[5] = f2bf(f1.y); tr[6] = f2bf(f1.z); tr[7] = f2bf(f1.w);
  tr[8] = f2bf(f2.x); tr[9] = f2bf(f2.y); tr[10] = f2bf(f2.z); tr[11] = f2bf(f2.w);
  tr[12] = f2bf(f3.x); tr[13] = f2bf(f3.y); tr[14] = f2bf(f3.z); tr[15] = f2bf(f3.w);
  __syncthreads();
  u16 o[16];
#pragma unroll
  for (int j = 0; j < 16; j++) o[j] = t[(ch * 16 + j) * 72 + r];
  u16* op = xbT + ((size_t)b * HW + p0 + r) * CIN + c0 + ch * 16;
  *(short8*)(op) = *(short8*)&o[0];
  *(short8*)(op + 8) = *(short8*)&o[8];
}

// ---------------------------------------------------------------------------
// weights -> bf16; wqk = [Wq*log2e; Wk] (128,512); bqk = [bq*log2e; bk]
// ---------------------------------------------------------------------------
__global__ void cast_w(const float* __restrict__ Wq, const float* __restrict__ Wk,
                       const float* __restrict__ Wv, const float* __restrict__ Wd,
                       const float* __restrict__ bq, const float* __restrict__ bk,
                       u16* __restrict__ wqk, u16* __restrict__ wv,
                       u16* __restrict__ wd, float* __restrict__ bqk) {
  const float LOG2E = 1.4426950408889634f;
  int i = blockIdx.x * 256 + threadIdx.x;
  if (i < 65536) wqk[i] = f2bf(i < 32768 ? Wq[i] * LOG2E : Wk[i - 32768]);
  if (i < 262144) { wv[i] = f2bf(Wv[i]); wd[i] = f2bf(Wd[i]); }
  if (i < 128) bqk[i] = (i < 64) ? bq[i] * LOG2E : bk[i - 64];
}

// ---------------------------------------------------------------------------
// Generic GEMM: C(M,N) = A(M,K) * BT(N,K)^T  (both bf16, K-contiguous rows)
// m97-style: 128x128 tile, BK=32, global_load_lds(16B) staging, 4 waves.
// (unchanged - proven R7/R8)
// ---------------------------------------------------------------------------
__global__ __launch_bounds__(256) void gemm_bf16(
    const u16* __restrict__ A, const u16* __restrict__ BT,
    const float* __restrict__ bias, void* __restrict__ out,
    int M, int N, int K, int mode) {
  __shared__ u16 la[128 * 32];
  __shared__ u16 lb[128 * 32];
  int tid = threadIdx.x;
  int w = tid >> 6, lane = tid & 63, m = lane & 15, g = lane >> 4;
  int wm = w >> 1, wn = w & 1;
  int m0 = blockIdx.y * 128, n0 = blockIdx.x * 128;
  int sr = lane >> 2, sc = (lane & 3) * 8;
  const u16* pa0 = A + (size_t)(m0 + w * 32 + sr) * K + sc;
  const u16* pa1 = pa0 + (size_t)16 * K;
  const u16* pb0 = BT + (size_t)(n0 + w * 32 + sr) * K + sc;
  const u16* pb1 = pb0 + (size_t)16 * K;
  u16* la0 = &la[(w * 32) * 32];
  u16* la1 = &la[(w * 32 + 16) * 32];
  u16* lb0 = &lb[(w * 32) * 32];
  u16* lb1 = &lb[(w * 32 + 16) * 32];

  f32x4 acc[4][4];
  f32x4 zero = {0.f, 0.f, 0.f, 0.f};
#pragma unroll
  for (int i = 0; i < 4; i++)
#pragma unroll
    for (int j = 0; j < 4; j++) acc[i][j] = zero;

  for (int k0 = 0; k0 < K; k0 += 32) {
    __syncthreads();
    GL16(pa0 + k0, la0);
    GL16(pa1 + k0, la1);
    GL16(pb0 + k0, lb0);
    GL16(pb1 + k0, lb1);
    __syncthreads();
    short8 af[4], bf[4];
#pragma unroll
    for (int i = 0; i < 4; i++)
      af[i] = *(const short8*)&la[(wm * 64 + i * 16 + m) * 32 + g * 8];
#pragma unroll
    for (int j = 0; j < 4; j++)
      bf[j] = *(const short8*)&lb[(wn * 64 + j * 16 + m) * 32 + g * 8];
#pragma unroll
    for (int i = 0; i < 4; i++)
#pragma unroll
      for (int j = 0; j < 4; j++)
        acc[i][j] = __builtin_amdgcn_mfma_f32_16x16x32_bf16(af[i], bf[j], acc[i][j], 0, 0, 0);
  }

#pragma unroll
  for (int i = 0; i < 4; i++) {
#pragma unroll
    for (int j = 0; j < 4; j++) {
      int row_l = m0 + wm * 64 + i * 16 + g * 4;
      int col = n0 + wn * 64 + j * 16 + m;
#pragma unroll
      for (int r = 0; r < 4; r++) {
        int row = row_l + r;
        float v = acc[i][j][r];
        if (mode == 0) {
          v += bias[col];
          ((u16*)out)[(size_t)row * N + col] = f2bf(v);
        } else {
          v += bias[row];
          size_t addr = ((size_t)(col >> 12) * M + row) * HW + (col & (HW - 1));
          if (mode == 1) ((u16*)out)[addr] = f2bf(v);
          else           ((float*)out)[addr] = v;
        }
      }
    }
  }
}

// ---------------------------------------------------------------------------
// ppass: P = exp2(Q K^T) materialized bf16 + exact row-sum reciprocals.
// (unchanged - proven R7)
// ---------------------------------------------------------------------------
__global__ __launch_bounds__(512) void ppass(
    const u16* __restrict__ qkT, u16* __restrict__ P,
    float* __restrict__ li, int b0) {
  __shared__ u16 kl[256 * 64];
  __shared__ float red[2][64];
  int tid = threadIdx.x;
  int w = tid >> 6, lane = tid & 63, m = lane & 15, g = lane >> 4;
  int blk = blockIdx.x;
  int bb = blk >> 6, b = b0 + bb;
  int q0 = (blk & 63) << 6;
  int qg = w & 3, jh = w >> 2;
  size_t qrow = (size_t)b * HW + q0;

  short8 aq[2];
#pragma unroll
  for (int ks = 0; ks < 2; ks++)
    aq[ks] = *(const short8*)(qkT + (qrow + qg * 16 + m) * 128 + ks * 32 + g * 8);

  float lr[4] = {0.f, 0.f, 0.f, 0.f};
  u16* Pb = P + ((size_t)bb * HW + q0) * HW;
  const u16* kb = qkT + (size_t)b * HW * 128 + 64;
  f32x4 zero = {0.f, 0.f, 0.f, 0.f};

  for (int jp = 0; jp < 16; jp++) {
    int j0 = jp * 256;
    __syncthreads();
#pragma unroll
    for (int it = 0; it < 4; it++) {
      int c = tid + it * 512;
      int row = c >> 3, seg = c & 7;
      short8 v = *(const short8*)(kb + (size_t)(j0 + row) * 128 + seg * 8);
      *(short8*)&kl[row * 64 + ((seg ^ (row & 7)) * 8)] = v;
    }
    __syncthreads();
#pragma unroll
    for (int jt = 0; jt < 8; jt++) {
      int jr = jh * 128 + jt * 16;
      int krow = jr + m;
      f32x4 s = zero;
#pragma unroll
      for (int ks = 0; ks < 2; ks++) {
        short8 bk = *(const short8*)&kl[krow * 64 + (((ks * 4 + g) ^ (krow & 7)) * 8)];
        s = __builtin_amdgcn_mfma_f32_16x16x32_bf16(aq[ks], bk, s, 0, 0, 0);
      }
      int j = j0 + jr + m;
#pragma unroll
      for (int r = 0; r < 4; r++) {
        float p = exp2f(s[r]);
        lr[r] += p;
        Pb[(size_t)(qg * 16 + g * 4 + r) * HW + j] = f2bf(p);
      }
    }
  }
#pragma unroll
  for (int r = 0; r < 4; r++) {
#pragma unroll
    for (int off = 1; off < 16; off <<= 1)
      lr[r] += __shfl_xor(lr[r], off);
  }
  __syncthreads();
  if (m == 0) {
#pragma unroll
    for (int r = 0; r < 4; r++) red[jh][qg * 16 + g * 4 + r] = lr[r];
  }
  __syncthreads();
  if (tid < 64) li[qrow + tid] = 1.0f / (red[0][tid] + red[1][tid]);
}

// ---------------------------------------------------------------------------
// gemm_pv: uT = gamma * (P * V^T) .* li + xbT.
// PROVEN m97 structure (single-buffer, 2 barriers/K-step, linear LDS,
// global_load_lds 16B) - only the tiling/grid differ from R7:
//   tile 64q x 256c, 4 waves (each 64q x 64c = 4x4 frags), BK=32.
//   grid (2 chan-halves, 64 q-tiles, nb) = 512 blocks (2/CU).
// Bijective chunked XCD swizzle: adjacent work ids (the two chan-halves of
// one P-panel) land on the SAME XCD -> P panel shared in L2; each XCD's
// 64-work chunk covers one batch -> its 4MB V fits L2 exactly.
// A tile (P rows) staged by all 4 waves (16 rows each); B tile (V rows)
// 4 GL16/wave. P logical read 2x (second mostly L2/L3).
// ---------------------------------------------------------------------------
__global__ __launch_bounds__(256) void gemm_pv(
    const u16* __restrict__ P, const u16* __restrict__ V,
    const float* __restrict__ li, const u16* __restrict__ xbT,
    const float* __restrict__ gamma, u16* __restrict__ uT, int b0) {
  __shared__ u16 la[64 * 32];
  __shared__ u16 lb[256 * 32];
  int tid = threadIdx.x;
  int w = tid >> 6, lane = tid & 63, m = lane & 15, g = lane >> 4;
  // bijective chunk swizzle over the linearized grid (total = 128*nb, %8==0)
  int total = gridDim.x * gridDim.y * gridDim.z;
  int lid = blockIdx.x + (blockIdx.y << 1) + (blockIdx.z << 7);
  int wk = (lid & 7) * (total >> 3) + (lid >> 3);
  int chan = (wk & 1) << 8;          // 0 or 256
  int q0 = ((wk >> 1) & 63) << 6;    // q-tile
  int bb = wk >> 7, b = b0 + bb;
  int sr = lane >> 2, sc = (lane & 3) << 3;

  const u16* pa = P + ((size_t)bb * HW + q0 + w * 16 + sr) * HW + sc;
  const u16* pv = V + ((size_t)b * CIN + chan + w * 64 + sr) * HW + sc;
  u16* lad = &la[(w * 16) * 32];

  f32x4 acc[4][4];
  f32x4 zero = {0.f, 0.f, 0.f, 0.f};
#pragma unroll
  for (int i = 0; i < 4; i++)
#pragma unroll
    for (int j = 0; j < 4; j++) acc[i][j] = zero;

  for (int k0 = 0; k0 < HW; k0 += 32) {
    __syncthreads();
    GL16(pa + k0, lad);
#pragma unroll
    for (int t = 0; t < 4; t++)
      GL16(pv + (size_t)(t * 16) * HW + k0, &lb[(w * 64 + t * 16) * 32]);
    __syncthreads();
    short8 af[4], bf[4];
#pragma unroll
    for (int i = 0; i < 4; i++)
      af[i] = *(const short8*)&la[(i * 16 + m) * 32 + g * 8];
#pragma unroll
    for (int j = 0; j < 4; j++)
      bf[j] = *(const short8*)&lb[(w * 64 + j * 16 + m) * 32 + g * 8];
#pragma unroll
    for (int i = 0; i < 4; i++)
#pragma unroll
      for (int j = 0; j < 4; j++)
        acc[i][j] = __builtin_amdgcn_mfma_f32_16x16x32_bf16(af[i], bf[j], acc[i][j], 0, 0, 0);
  }

  float gm = gamma[0];
#pragma unroll
  for (int i = 0; i < 4; i++) {
#pragma unroll
    for (int j = 0; j < 4; j++) {
#pragma unroll
      for (int r = 0; r < 4; r++) {
        int q = q0 + i * 16 + g * 4 + r;
        int c = chan + w * 64 + j * 16 + m;
        size_t row = (size_t)b * HW + q;
        float o = acc[i][j][r] * li[row];
        float xv = bf2f(xbT[row * CIN + c]);
        uT[row * CIN + c] = f2bf(gm * o + xv);
      }
    }
  }
}

// ---------------------------------------------------------------------------
extern "C" void kernel_launch(void* const* d_in, const int* in_sizes, int n_in,
                              void* d_out, int out_size, void* d_ws, size_t ws_size,
                              hipStream_t stream) {
  const float* x     = (const float*)d_in[0];
  const float* Wq    = (const float*)d_in[1];
  const float* bq    = (const float*)d_in[2];
  const float* Wk    = (const float*)d_in[3];
  const float* bk    = (const float*)d_in[4];
  const float* Wv    = (const float*)d_in[5];
  const float* bv    = (const float*)d_in[6];
  const float* gamma = (const float*)d_in[7];
  const float* Wd    = (const float*)d_in[8];
  const float* bd    = (const float*)d_in[9];

  char* ws = (char*)d_ws;
  size_t off = 0;
  auto alloc = [&](size_t bytes) {
    void* p = ws + off;
    off += (bytes + 255) & ~(size_t)255;
    return p;
  };
  u16*   xbT = (u16*)alloc((size_t)16384 * 512 * 2);
  u16*   qkT = (u16*)alloc((size_t)16384 * 128 * 2);
  u16*   vb  = (u16*)alloc((size_t)16384 * 512 * 2);
  u16*   uT  = (u16*)alloc((size_t)16384 * 512 * 2);
  u16*   wqk = (u16*)alloc((size_t)65536 * 2);
  u16*   wvb = (u16*)alloc((size_t)262144 * 2);
  u16*   wdb = (u16*)alloc((size_t)262144 * 2);
  float* bqk = (float*)alloc(128 * 4);
  float* li  = (float*)alloc((size_t)16384 * 4);
  size_t PB = (size_t)HW * HW * 2;
  int nb = 0;
  if      (off + 4 * PB <= ws_size) nb = 4;
  else if (off + 2 * PB <= ws_size) nb = 2;
  else if (off + 1 * PB <= ws_size) nb = 1;
  if (nb == 0) return;  // workspace too small -> poison stays -> loud failure
  u16* Pbuf = (u16*)alloc(nb * PB);

  cast_xT<<<dim3(64, 8, 4), 256, 0, stream>>>(x, xbT);
  cast_w<<<1024, 256, 0, stream>>>(Wq, Wk, Wv, Wd, bq, bk, wqk, wvb, wdb, bqk);
  // qkT (16384,128) = xbT * wqk^T
  gemm_bf16<<<dim3(1, 128), 256, 0, stream>>>(xbT, wqk, bqk, qkT, 16384, 128, 512, 0);
  // v (B,512,HW) = Wv * x
  gemm_bf16<<<dim3(128, 4), 256, 0, stream>>>(wvb, xbT, bv, vb, 512, 16384, 512, 1);
  // attention: P materialize + PV GEMM (staged by batch groups of nb)
  for (int b0 = 0; b0 < 4; b0 += nb) {
    ppass<<<dim3(nb * 64), 512, 0, stream>>>(qkT, Pbuf, li, b0);
    gemm_pv<<<dim3(2, 64, nb), 256, 0, stream>>>(Pbuf, vb, li, xbT, gamma, uT, b0);
  }
  // pam_out (B,512,HW) fp32 = Wd * u
  gemm_bf16<<<dim3(128, 4), 256, 0, stream>>>(wdb, uT, bd, d_out, 512, 16384, 512, 2);
}

// Round 11
// 224.951 us; speedup vs baseline: 1.7711x; 1.0409x over previous
//
#include <hip/hip_runtime.h>
#include <stdint.h>

#define HW   4096
#define CIN  512

typedef __attribute__((ext_vector_type(8))) short short8;
typedef __attribute__((ext_vector_type(4))) float f32x4;
typedef unsigned short u16;

#define GL16(src, ldsdst) __builtin_amdgcn_global_load_lds(                    \
    (const __attribute__((address_space(1))) void*)(src),                      \
    (__attribute__((address_space(3))) void*)(ldsdst), 16, 0, 0)

__device__ __forceinline__ u16 f2bf(float f) {
  union { float f; uint32_t u; } c; c.f = f;
  uint32_t r = (c.u + 0x7FFFu + ((c.u >> 16) & 1u)) >> 16;
  return (u16)r;
}
__device__ __forceinline__ float bf2f(u16 h) {
  union { uint32_t u; float f; } c; c.u = ((uint32_t)h) << 16;
  return c.f;
}

// ---------------------------------------------------------------------------
// x (B,C,HW) fp32  ->  xbT (B*HW, C) bf16   (64x64 tile transpose via LDS)
// ---------------------------------------------------------------------------
__global__ __launch_bounds__(256) void cast_xT(const float* __restrict__ x,
                                               u16* __restrict__ xbT) {
  __shared__ u16 t[64 * 72];
  int p0 = blockIdx.x * 64, c0 = blockIdx.y * 64, b = blockIdx.z;
  int tid = threadIdx.x, r = tid >> 2, ch = tid & 3;
  const float* xp = x + ((size_t)b * CIN + c0 + r) * HW + p0 + ch * 16;
  float4 f0 = *(const float4*)(xp + 0);
  float4 f1 = *(const float4*)(xp + 4);
  float4 f2 = *(const float4*)(xp + 8);
  float4 f3 = *(const float4*)(xp + 12);
  u16* tr = &t[r * 72 + ch * 16];
  tr[0] = f2bf(f0.x); tr[1] = f2bf(f0.y); tr[2] = f2bf(f0.z); tr[3] = f2bf(f0.w);
  tr[4] = f2bf(f1.x); tr[5] = f2bf(f1.y); tr[6] = f2bf(f1.z); tr[7] = f2bf(f1.w);
  tr[8] = f2bf(f2.x); tr[9] = f2bf(f2.y); tr[10] = f2bf(f2.z); tr[11] = f2bf(f2.w);
  tr[12] = f2bf(f3.x); tr[13] = f2bf(f3.y); tr[14] = f2bf(f3.z); tr[15] = f2bf(f3.w);
  __syncthreads();
  u16 o[16];
#pragma unroll
  for (int j = 0; j < 16; j++) o[j] = t[(ch * 16 + j) * 72 + r];
  u16* op = xbT + ((size_t)b * HW + p0 + r) * CIN + c0 + ch * 16;
  *(short8*)(op) = *(short8*)&o[0];
  *(short8*)(op + 8) = *(short8*)&o[8];
}

// ---------------------------------------------------------------------------
// weights -> bf16; wqk = [Wq*log2e; Wk] (128,512); bqk = [bq*log2e; bk]
// ---------------------------------------------------------------------------
__global__ void cast_w(const float* __restrict__ Wq, const float* __restrict__ Wk,
                       const float* __restrict__ Wv, const float* __restrict__ Wd,
                       const float* __restrict__ bq, const float* __restrict__ bk,
                       u16* __restrict__ wqk, u16* __restrict__ wv,
                       u16* __restrict__ wd, float* __restrict__ bqk) {
  const float LOG2E = 1.4426950408889634f;
  int i = blockIdx.x * 256 + threadIdx.x;
  if (i < 65536) wqk[i] = f2bf(i < 32768 ? Wq[i] * LOG2E : Wk[i - 32768]);
  if (i < 262144) { wv[i] = f2bf(Wv[i]); wd[i] = f2bf(Wd[i]); }
  if (i < 128) bqk[i] = (i < 64) ? bq[i] * LOG2E : bk[i - 64];
}

// ---------------------------------------------------------------------------
// Generic GEMM: C(M,N) = A(M,K) * BT(N,K)^T  (both bf16, K-contiguous rows)
// m97-style: 128x128 tile, BK=32, global_load_lds(16B) staging, 4 waves.
// (unchanged - proven R7/R8/R10)
// ---------------------------------------------------------------------------
__global__ __launch_bounds__(256) void gemm_bf16(
    const u16* __restrict__ A, const u16* __restrict__ BT,
    const float* __restrict__ bias, void* __restrict__ out,
    int M, int N, int K, int mode) {
  __shared__ u16 la[128 * 32];
  __shared__ u16 lb[128 * 32];
  int tid = threadIdx.x;
  int w = tid >> 6, lane = tid & 63, m = lane & 15, g = lane >> 4;
  int wm = w >> 1, wn = w & 1;
  int m0 = blockIdx.y * 128, n0 = blockIdx.x * 128;
  int sr = lane >> 2, sc = (lane & 3) * 8;
  const u16* pa0 = A + (size_t)(m0 + w * 32 + sr) * K + sc;
  const u16* pa1 = pa0 + (size_t)16 * K;
  const u16* pb0 = BT + (size_t)(n0 + w * 32 + sr) * K + sc;
  const u16* pb1 = pb0 + (size_t)16 * K;
  u16* la0 = &la[(w * 32) * 32];
  u16* la1 = &la[(w * 32 + 16) * 32];
  u16* lb0 = &lb[(w * 32) * 32];
  u16* lb1 = &lb[(w * 32 + 16) * 32];

  f32x4 acc[4][4];
  f32x4 zero = {0.f, 0.f, 0.f, 0.f};
#pragma unroll
  for (int i = 0; i < 4; i++)
#pragma unroll
    for (int j = 0; j < 4; j++) acc[i][j] = zero;

  for (int k0 = 0; k0 < K; k0 += 32) {
    __syncthreads();
    GL16(pa0 + k0, la0);
    GL16(pa1 + k0, la1);
    GL16(pb0 + k0, lb0);
    GL16(pb1 + k0, lb1);
    __syncthreads();
    short8 af[4], bf[4];
#pragma unroll
    for (int i = 0; i < 4; i++)
      af[i] = *(const short8*)&la[(wm * 64 + i * 16 + m) * 32 + g * 8];
#pragma unroll
    for (int j = 0; j < 4; j++)
      bf[j] = *(const short8*)&lb[(wn * 64 + j * 16 + m) * 32 + g * 8];
#pragma unroll
    for (int i = 0; i < 4; i++)
#pragma unroll
      for (int j = 0; j < 4; j++)
        acc[i][j] = __builtin_amdgcn_mfma_f32_16x16x32_bf16(af[i], bf[j], acc[i][j], 0, 0, 0);
  }

#pragma unroll
  for (int i = 0; i < 4; i++) {
#pragma unroll
    for (int j = 0; j < 4; j++) {
      int row_l = m0 + wm * 64 + i * 16 + g * 4;
      int col = n0 + wn * 64 + j * 16 + m;
#pragma unroll
      for (int r = 0; r < 4; r++) {
        int row = row_l + r;
        float v = acc[i][j][r];
        if (mode == 0) {
          v += bias[col];
          ((u16*)out)[(size_t)row * N + col] = f2bf(v);
        } else {
          v += bias[row];
          size_t addr = ((size_t)(col >> 12) * M + row) * HW + (col & (HW - 1));
          if (mode == 1) ((u16*)out)[addr] = f2bf(v);
          else           ((float*)out)[addr] = v;
        }
      }
    }
  }
}

// ---------------------------------------------------------------------------
// ppass: P = exp2(Q K^T) materialized bf16 + exact row-sum reciprocals.
// (unchanged - proven R7/R10)
// ---------------------------------------------------------------------------
__global__ __launch_bounds__(512) void ppass(
    const u16* __restrict__ qkT, u16* __restrict__ P,
    float* __restrict__ li, int b0) {
  __shared__ u16 kl[256 * 64];
  __shared__ float red[2][64];
  int tid = threadIdx.x;
  int w = tid >> 6, lane = tid & 63, m = lane & 15, g = lane >> 4;
  int blk = blockIdx.x;
  int bb = blk >> 6, b = b0 + bb;
  int q0 = (blk & 63) << 6;
  int qg = w & 3, jh = w >> 2;
  size_t qrow = (size_t)b * HW + q0;

  short8 aq[2];
#pragma unroll
  for (int ks = 0; ks < 2; ks++)
    aq[ks] = *(const short8*)(qkT + (qrow + qg * 16 + m) * 128 + ks * 32 + g * 8);

  float lr[4] = {0.f, 0.f, 0.f, 0.f};
  u16* Pb = P + ((size_t)bb * HW + q0) * HW;
  const u16* kb = qkT + (size_t)b * HW * 128 + 64;
  f32x4 zero = {0.f, 0.f, 0.f, 0.f};

  for (int jp = 0; jp < 16; jp++) {
    int j0 = jp * 256;
    __syncthreads();
#pragma unroll
    for (int it = 0; it < 4; it++) {
      int c = tid + it * 512;
      int row = c >> 3, seg = c & 7;
      short8 v = *(const short8*)(kb + (size_t)(j0 + row) * 128 + seg * 8);
      *(short8*)&kl[row * 64 + ((seg ^ (row & 7)) * 8)] = v;
    }
    __syncthreads();
#pragma unroll
    for (int jt = 0; jt < 8; jt++) {
      int jr = jh * 128 + jt * 16;
      int krow = jr + m;
      f32x4 s = zero;
#pragma unroll
      for (int ks = 0; ks < 2; ks++) {
        short8 bk = *(const short8*)&kl[krow * 64 + (((ks * 4 + g) ^ (krow & 7)) * 8)];
        s = __builtin_amdgcn_mfma_f32_16x16x32_bf16(aq[ks], bk, s, 0, 0, 0);
      }
      int j = j0 + jr + m;
#pragma unroll
      for (int r = 0; r < 4; r++) {
        float p = exp2f(s[r]);
        lr[r] += p;
        Pb[(size_t)(qg * 16 + g * 4 + r) * HW + j] = f2bf(p);
      }
    }
  }
#pragma unroll
  for (int r = 0; r < 4; r++) {
#pragma unroll
    for (int off = 1; off < 16; off <<= 1)
      lr[r] += __shfl_xor(lr[r], off);
  }
  __syncthreads();
  if (m == 0) {
#pragma unroll
    for (int r = 0; r < 4; r++) red[jh][qg * 16 + g * 4 + r] = lr[r];
  }
  __syncthreads();
  if (tid < 64) li[qrow + tid] = 1.0f / (red[0][tid] + red[1][tid]);
}

// ---------------------------------------------------------------------------
// gemm_pv: uT = gamma * (P * V^T) .* li + xbT.
// PROVEN m97 staging (single-buffer, 2 barriers/K-step, linear LDS,
// global_load_lds 16B). ONLY change vs R10: finer partition for occupancy.
//   tile 64q x 128c, 4 waves (2x2, wave tile 32q x 64c = 2x4 frags), BK=32.
//   grid (4 chan-quarters, 64 q-tiles, nb) = 1024 blocks -> 4 blocks/CU.
//   LDS 12 KB/block; 3 GL16/thread/K-step.
// 4 independent blocks per CU interleave stage/compute -> barrier drain of
// one block hides under MFMA of the others (m97 ran 3-4 blocks/CU at 37%).
// Chunked bijective XCD swizzle keeps the 4 chan-quarters of each P-panel
// adjacent (same XCD, panel slice 512 KB in L2 -> P fetched ~once) and one
// batch's V (4 MB) per XCD.
// ---------------------------------------------------------------------------
__global__ __launch_bounds__(256) void gemm_pv(
    const u16* __restrict__ P, const u16* __restrict__ V,
    const float* __restrict__ li, const u16* __restrict__ xbT,
    const float* __restrict__ gamma, u16* __restrict__ uT, int b0) {
  __shared__ u16 la[64 * 32];
  __shared__ u16 lb[128 * 32];
  int tid = threadIdx.x;
  int w = tid >> 6, lane = tid & 63, m = lane & 15, g = lane >> 4;
  int wm = w >> 1, wn = w & 1;
  // bijective chunk swizzle over linearized grid (total = 256*nb, %8==0)
  int total = gridDim.x * gridDim.y * gridDim.z;
  int lid = blockIdx.x + (blockIdx.y << 2) + (blockIdx.z << 8);
  int wk = (lid & 7) * (total >> 3) + (lid >> 3);
  int chan = (wk & 3) << 7;          // 0,128,256,384
  int q0 = ((wk >> 2) & 63) << 6;    // q-tile
  int bb = wk >> 8, b = b0 + bb;
  int sr = lane >> 2, sc = (lane & 3) << 3;

  const u16* pa = P + ((size_t)bb * HW + q0 + w * 16 + sr) * HW + sc;
  const u16* pv = V + ((size_t)b * CIN + chan + w * 32 + sr) * HW + sc;
  u16* lad  = &la[(w * 16) * 32];
  u16* lbd0 = &lb[(w * 32) * 32];
  u16* lbd1 = &lb[(w * 32 + 16) * 32];

  f32x4 acc[2][4];
  f32x4 zero = {0.f, 0.f, 0.f, 0.f};
#pragma unroll
  for (int i = 0; i < 2; i++)
#pragma unroll
    for (int j = 0; j < 4; j++) acc[i][j] = zero;

  for (int k0 = 0; k0 < HW; k0 += 32) {
    __syncthreads();
    GL16(pa + k0, lad);
    GL16(pv + k0, lbd0);
    GL16(pv + (size_t)16 * HW + k0, lbd1);
    __syncthreads();
    short8 af[2], bf[4];
#pragma unroll
    for (int i = 0; i < 2; i++)
      af[i] = *(const short8*)&la[(wm * 32 + i * 16 + m) * 32 + g * 8];
#pragma unroll
    for (int j = 0; j < 4; j++)
      bf[j] = *(const short8*)&lb[(wn * 64 + j * 16 + m) * 32 + g * 8];
#pragma unroll
    for (int i = 0; i < 2; i++)
#pragma unroll
      for (int j = 0; j < 4; j++)
        acc[i][j] = __builtin_amdgcn_mfma_f32_16x16x32_bf16(af[i], bf[j], acc[i][j], 0, 0, 0);
  }

  float gm = gamma[0];
#pragma unroll
  for (int i = 0; i < 2; i++) {
#pragma unroll
    for (int j = 0; j < 4; j++) {
#pragma unroll
      for (int r = 0; r < 4; r++) {
        int q = q0 + wm * 32 + i * 16 + g * 4 + r;
        int c = chan + wn * 64 + j * 16 + m;
        size_t row = (size_t)b * HW + q;
        float o = acc[i][j][r] * li[row];
        float xv = bf2f(xbT[row * CIN + c]);
        uT[row * CIN + c] = f2bf(gm * o + xv);
      }
    }
  }
}

// ---------------------------------------------------------------------------
extern "C" void kernel_launch(void* const* d_in, const int* in_sizes, int n_in,
                              void* d_out, int out_size, void* d_ws, size_t ws_size,
                              hipStream_t stream) {
  const float* x     = (const float*)d_in[0];
  const float* Wq    = (const float*)d_in[1];
  const float* bq    = (const float*)d_in[2];
  const float* Wk    = (const float*)d_in[3];
  const float* bk    = (const float*)d_in[4];
  const float* Wv    = (const float*)d_in[5];
  const float* bv    = (const float*)d_in[6];
  const float* gamma = (const float*)d_in[7];
  const float* Wd    = (const float*)d_in[8];
  const float* bd    = (const float*)d_in[9];

  char* ws = (char*)d_ws;
  size_t off = 0;
  auto alloc = [&](size_t bytes) {
    void* p = ws + off;
    off += (bytes + 255) & ~(size_t)255;
    return p;
  };
  u16*   xbT = (u16*)alloc((size_t)16384 * 512 * 2);
  u16*   qkT = (u16*)alloc((size_t)16384 * 128 * 2);
  u16*   vb  = (u16*)alloc((size_t)16384 * 512 * 2);
  u16*   uT  = (u16*)alloc((size_t)16384 * 512 * 2);
  u16*   wqk = (u16*)alloc((size_t)65536 * 2);
  u16*   wvb = (u16*)alloc((size_t)262144 * 2);
  u16*   wdb = (u16*)alloc((size_t)262144 * 2);
  float* bqk = (float*)alloc(128 * 4);
  float* li  = (float*)alloc((size_t)16384 * 4);
  size_t PB = (size_t)HW * HW * 2;
  int nb = 0;
  if      (off + 4 * PB <= ws_size) nb = 4;
  else if (off + 2 * PB <= ws_size) nb = 2;
  else if (off + 1 * PB <= ws_size) nb = 1;
  if (nb == 0) return;  // workspace too small -> poison stays -> loud failure
  u16* Pbuf = (u16*)alloc(nb * PB);

  cast_xT<<<dim3(64, 8, 4), 256, 0, stream>>>(x, xbT);
  cast_w<<<1024, 256, 0, stream>>>(Wq, Wk, Wv, Wd, bq, bk, wqk, wvb, wdb, bqk);
  // qkT (16384,128) = xbT * wqk^T
  gemm_bf16<<<dim3(1, 128), 256, 0, stream>>>(xbT, wqk, bqk, qkT, 16384, 128, 512, 0);
  // v (B,512,HW) = Wv * x
  gemm_bf16<<<dim3(128, 4), 256, 0, stream>>>(wvb, xbT, bv, vb, 512, 16384, 512, 1);
  // attention: P materialize + PV GEMM (staged by batch groups of nb)
  for (int b0 = 0; b0 < 4; b0 += nb) {
    ppass<<<dim3(nb * 64), 512, 0, stream>>>(qkT, Pbuf, li, b0);
    gemm_pv<<<dim3(4, 64, nb), 256, 0, stream>>>(Pbuf, vb, li, xbT, gamma, uT, b0);
  }
  // pam_out (B,512,HW) fp32 = Wd * u
  gemm_bf16<<<dim3(128, 4), 256, 0, stream>>>(wdb, uT, bd, d_out, 512, 16384, 512, 2);
}

// Round 12
// 221.651 us; speedup vs baseline: 1.7974x; 1.0149x over previous
//
#include <hip/hip_runtime.h>
#include <stdint.h>

#define HW   4096
#define CIN  512

typedef __attribute__((ext_vector_type(8))) short short8;
typedef __attribute__((ext_vector_type(4))) float f32x4;
typedef unsigned short u16;

#define GL16(src, ldsdst) __builtin_amdgcn_global_load_lds(                    \
    (const __attribute__((address_space(1))) void*)(src),                      \
    (__attribute__((address_space(3))) void*)(ldsdst), 16, 0, 0)

__device__ __forceinline__ u16 f2bf(float f) {
  union { float f; uint32_t u; } c; c.f = f;
  uint32_t r = (c.u + 0x7FFFu + ((c.u >> 16) & 1u)) >> 16;
  return (u16)r;
}
__device__ __forceinline__ float bf2f(u16 h) {
  union { uint32_t u; float f; } c; c.u = ((uint32_t)h) << 16;
  return c.f;
}

// ---------------------------------------------------------------------------
// x (B,C,HW) fp32  ->  xbT (B*HW, C) bf16   (64x64 tile transpose via LDS)
// ---------------------------------------------------------------------------
__global__ __launch_bounds__(256) void cast_xT(const float* __restrict__ x,
                                               u16* __restrict__ xbT) {
  __shared__ u16 t[64 * 72];
  int p0 = blockIdx.x * 64, c0 = blockIdx.y * 64, b = blockIdx.z;
  int tid = threadIdx.x, r = tid >> 2, ch = tid & 3;
  const float* xp = x + ((size_t)b * CIN + c0 + r) * HW + p0 + ch * 16;
  float4 f0 = *(const float4*)(xp + 0);
  float4 f1 = *(const float4*)(xp + 4);
  float4 f2 = *(const float4*)(xp + 8);
  float4 f3 = *(const float4*)(xp + 12);
  u16* tr = &t[r * 72 + ch * 16];
  tr[0] = f2bf(f0.x); tr[1] = f2bf(f0.y); tr[2] = f2bf(f0.z); tr[3] = f2bf(f0.w);
  tr[4] = f2bf(f1.x); tr[5] = f2bf(f1.y); tr[6] = f2bf(f1.z); tr[7] = f2bf(f1.w);
  tr[8] = f2bf(f2.x); tr[9] = f2bf(f2.y); tr[10] = f2bf(f2.z); tr[11] = f2bf(f2.w);
  tr[12] = f2bf(f3.x); tr[13] = f2bf(f3.y); tr[14] = f2bf(f3.z); tr[15] = f2bf(f3.w);
  __syncthreads();
  u16 o[16];
#pragma unroll
  for (int j = 0; j < 16; j++) o[j] = t[(ch * 16 + j) * 72 + r];
  u16* op = xbT + ((size_t)b * HW + p0 + r) * CIN + c0 + ch * 16;
  *(short8*)(op) = *(short8*)&o[0];
  *(short8*)(op + 8) = *(short8*)&o[8];
}

// ---------------------------------------------------------------------------
// weights -> bf16; wqk = [Wq*log2e; Wk] (128,512); bqk = [bq*log2e; bk]
// ---------------------------------------------------------------------------
__global__ void cast_w(const float* __restrict__ Wq, const float* __restrict__ Wk,
                       const float* __restrict__ Wv, const float* __restrict__ Wd,
                       const float* __restrict__ bq, const float* __restrict__ bk,
                       u16* __restrict__ wqk, u16* __restrict__ wv,
                       u16* __restrict__ wd, float* __restrict__ bqk) {
  const float LOG2E = 1.4426950408889634f;
  int i = blockIdx.x * 256 + threadIdx.x;
  if (i < 65536) wqk[i] = f2bf(i < 32768 ? Wq[i] * LOG2E : Wk[i - 32768]);
  if (i < 262144) { wv[i] = f2bf(Wv[i]); wd[i] = f2bf(Wd[i]); }
  if (i < 128) bqk[i] = (i < 64) ? bq[i] * LOG2E : bk[i - 64];
}

// ---------------------------------------------------------------------------
// Generic GEMM: C(M,N) = A(M,K) * BT(N,K)^T  (both bf16, K-contiguous rows)
// m97-style: 128x128 tile, BK=32, global_load_lds(16B) staging, 4 waves.
// (unchanged - proven R7/R8/R10/R11)
// ---------------------------------------------------------------------------
__global__ __launch_bounds__(256) void gemm_bf16(
    const u16* __restrict__ A, const u16* __restrict__ BT,
    const float* __restrict__ bias, void* __restrict__ out,
    int M, int N, int K, int mode) {
  __shared__ u16 la[128 * 32];
  __shared__ u16 lb[128 * 32];
  int tid = threadIdx.x;
  int w = tid >> 6, lane = tid & 63, m = lane & 15, g = lane >> 4;
  int wm = w >> 1, wn = w & 1;
  int m0 = blockIdx.y * 128, n0 = blockIdx.x * 128;
  int sr = lane >> 2, sc = (lane & 3) * 8;
  const u16* pa0 = A + (size_t)(m0 + w * 32 + sr) * K + sc;
  const u16* pa1 = pa0 + (size_t)16 * K;
  const u16* pb0 = BT + (size_t)(n0 + w * 32 + sr) * K + sc;
  const u16* pb1 = pb0 + (size_t)16 * K;
  u16* la0 = &la[(w * 32) * 32];
  u16* la1 = &la[(w * 32 + 16) * 32];
  u16* lb0 = &lb[(w * 32) * 32];
  u16* lb1 = &lb[(w * 32 + 16) * 32];

  f32x4 acc[4][4];
  f32x4 zero = {0.f, 0.f, 0.f, 0.f};
#pragma unroll
  for (int i = 0; i < 4; i++)
#pragma unroll
    for (int j = 0; j < 4; j++) acc[i][j] = zero;

  for (int k0 = 0; k0 < K; k0 += 32) {
    __syncthreads();
    GL16(pa0 + k0, la0);
    GL16(pa1 + k0, la1);
    GL16(pb0 + k0, lb0);
    GL16(pb1 + k0, lb1);
    __syncthreads();
    short8 af[4], bf[4];
#pragma unroll
    for (int i = 0; i < 4; i++)
      af[i] = *(const short8*)&la[(wm * 64 + i * 16 + m) * 32 + g * 8];
#pragma unroll
    for (int j = 0; j < 4; j++)
      bf[j] = *(const short8*)&lb[(wn * 64 + j * 16 + m) * 32 + g * 8];
#pragma unroll
    for (int i = 0; i < 4; i++)
#pragma unroll
      for (int j = 0; j < 4; j++)
        acc[i][j] = __builtin_amdgcn_mfma_f32_16x16x32_bf16(af[i], bf[j], acc[i][j], 0, 0, 0);
  }

#pragma unroll
  for (int i = 0; i < 4; i++) {
#pragma unroll
    for (int j = 0; j < 4; j++) {
      int row_l = m0 + wm * 64 + i * 16 + g * 4;
      int col = n0 + wn * 64 + j * 16 + m;
#pragma unroll
      for (int r = 0; r < 4; r++) {
        int row = row_l + r;
        float v = acc[i][j][r];
        if (mode == 0) {
          v += bias[col];
          ((u16*)out)[(size_t)row * N + col] = f2bf(v);
        } else {
          v += bias[row];
          size_t addr = ((size_t)(col >> 12) * M + row) * HW + (col & (HW - 1));
          if (mode == 1) ((u16*)out)[addr] = f2bf(v);
          else           ((float*)out)[addr] = v;
        }
      }
    }
  }
}

// ---------------------------------------------------------------------------
// ppass: P = exp2(Q K^T) materialized bf16 + exact row-sum reciprocals.
// (unchanged - proven R7/R10/R11)
// ---------------------------------------------------------------------------
__global__ __launch_bounds__(512) void ppass(
    const u16* __restrict__ qkT, u16* __restrict__ P,
    float* __restrict__ li, int b0) {
  __shared__ u16 kl[256 * 64];
  __shared__ float red[2][64];
  int tid = threadIdx.x;
  int w = tid >> 6, lane = tid & 63, m = lane & 15, g = lane >> 4;
  int blk = blockIdx.x;
  int bb = blk >> 6, b = b0 + bb;
  int q0 = (blk & 63) << 6;
  int qg = w & 3, jh = w >> 2;
  size_t qrow = (size_t)b * HW + q0;

  short8 aq[2];
#pragma unroll
  for (int ks = 0; ks < 2; ks++)
    aq[ks] = *(const short8*)(qkT + (qrow + qg * 16 + m) * 128 + ks * 32 + g * 8);

  float lr[4] = {0.f, 0.f, 0.f, 0.f};
  u16* Pb = P + ((size_t)bb * HW + q0) * HW;
  const u16* kb = qkT + (size_t)b * HW * 128 + 64;
  f32x4 zero = {0.f, 0.f, 0.f, 0.f};

  for (int jp = 0; jp < 16; jp++) {
    int j0 = jp * 256;
    __syncthreads();
#pragma unroll
    for (int it = 0; it < 4; it++) {
      int c = tid + it * 512;
      int row = c >> 3, seg = c & 7;
      short8 v = *(const short8*)(kb + (size_t)(j0 + row) * 128 + seg * 8);
      *(short8*)&kl[row * 64 + ((seg ^ (row & 7)) * 8)] = v;
    }
    __syncthreads();
#pragma unroll
    for (int jt = 0; jt < 8; jt++) {
      int jr = jh * 128 + jt * 16;
      int krow = jr + m;
      f32x4 s = zero;
#pragma unroll
      for (int ks = 0; ks < 2; ks++) {
        short8 bk = *(const short8*)&kl[krow * 64 + (((ks * 4 + g) ^ (krow & 7)) * 8)];
        s = __builtin_amdgcn_mfma_f32_16x16x32_bf16(aq[ks], bk, s, 0, 0, 0);
      }
      int j = j0 + jr + m;
#pragma unroll
      for (int r = 0; r < 4; r++) {
        float p = exp2f(s[r]);
        lr[r] += p;
        Pb[(size_t)(qg * 16 + g * 4 + r) * HW + j] = f2bf(p);
      }
    }
  }
#pragma unroll
  for (int r = 0; r < 4; r++) {
#pragma unroll
    for (int off = 1; off < 16; off <<= 1)
      lr[r] += __shfl_xor(lr[r], off);
  }
  __syncthreads();
  if (m == 0) {
#pragma unroll
    for (int r = 0; r < 4; r++) red[jh][qg * 16 + g * 4 + r] = lr[r];
  }
  __syncthreads();
  if (tid < 64) li[qrow + tid] = 1.0f / (red[0][tid] + red[1][tid]);
}

// ---------------------------------------------------------------------------
// gemm_pv: uT = gamma * (P * V^T) .* li + xbT.
// R11 structure, ONLY change: 2 K-chunks per barrier pair.
//   stage(k, k+32) -> barrier -> compute(k) + compute(k+32) -> barrier.
// No cross-barrier pipelining (both chunks staged AND consumed inside one
// barrier pair - trivially race-free). Barrier-drain events halve: 128->64.
// LDS 24 KB (still 4+ blocks/CU). Same bank behavior, same addresses.
//   tile 64q x 128c, 4 waves (2x2, wave 32q x 64c = 2x4 frags).
//   grid (4 chan-quarters, 64 q-tiles, nb) = 1024 blocks -> 4 blocks/CU.
// Chunked bijective XCD swizzle (proven R10/R11): chan-quarters of each
// P-panel adjacent -> P fetched ~once; ~one batch's V per XCD.
// ---------------------------------------------------------------------------
__global__ __launch_bounds__(256) void gemm_pv(
    const u16* __restrict__ P, const u16* __restrict__ V,
    const float* __restrict__ li, const u16* __restrict__ xbT,
    const float* __restrict__ gamma, u16* __restrict__ uT, int b0) {
  __shared__ u16 la[2][64 * 32];
  __shared__ u16 lb[2][128 * 32];
  int tid = threadIdx.x;
  int w = tid >> 6, lane = tid & 63, m = lane & 15, g = lane >> 4;
  int wm = w >> 1, wn = w & 1;
  // bijective chunk swizzle over linearized grid (total = 256*nb, %8==0)
  int total = gridDim.x * gridDim.y * gridDim.z;
  int lid = blockIdx.x + (blockIdx.y << 2) + (blockIdx.z << 8);
  int wk = (lid & 7) * (total >> 3) + (lid >> 3);
  int chan = (wk & 3) << 7;          // 0,128,256,384
  int q0 = ((wk >> 2) & 63) << 6;    // q-tile
  int bb = wk >> 8, b = b0 + bb;
  int sr = lane >> 2, sc = (lane & 3) << 3;

  const u16* pa = P + ((size_t)bb * HW + q0 + w * 16 + sr) * HW + sc;
  const u16* pv = V + ((size_t)b * CIN + chan + w * 32 + sr) * HW + sc;

  f32x4 acc[2][4];
  f32x4 zero = {0.f, 0.f, 0.f, 0.f};
#pragma unroll
  for (int i = 0; i < 2; i++)
#pragma unroll
    for (int j = 0; j < 4; j++) acc[i][j] = zero;

  for (int k0 = 0; k0 < HW; k0 += 64) {
    __syncthreads();
    // stage both 32-k chunks
    GL16(pa + k0,                     &la[0][(w * 16) * 32]);
    GL16(pv + k0,                     &lb[0][(w * 32) * 32]);
    GL16(pv + (size_t)16 * HW + k0,   &lb[0][(w * 32 + 16) * 32]);
    GL16(pa + k0 + 32,                &la[1][(w * 16) * 32]);
    GL16(pv + k0 + 32,                &lb[1][(w * 32) * 32]);
    GL16(pv + (size_t)16 * HW + k0 + 32, &lb[1][(w * 32 + 16) * 32]);
    __syncthreads();
#pragma unroll
    for (int c = 0; c < 2; c++) {
      short8 af[2], bf[4];
#pragma unroll
      for (int i = 0; i < 2; i++)
        af[i] = *(const short8*)&la[c][(wm * 32 + i * 16 + m) * 32 + g * 8];
#pragma unroll
      for (int j = 0; j < 4; j++)
        bf[j] = *(const short8*)&lb[c][(wn * 64 + j * 16 + m) * 32 + g * 8];
#pragma unroll
      for (int i = 0; i < 2; i++)
#pragma unroll
        for (int j = 0; j < 4; j++)
          acc[i][j] = __builtin_amdgcn_mfma_f32_16x16x32_bf16(af[i], bf[j], acc[i][j], 0, 0, 0);
    }
  }

  float gm = gamma[0];
#pragma unroll
  for (int i = 0; i < 2; i++) {
#pragma unroll
    for (int j = 0; j < 4; j++) {
#pragma unroll
      for (int r = 0; r < 4; r++) {
        int q = q0 + wm * 32 + i * 16 + g * 4 + r;
        int c = chan + wn * 64 + j * 16 + m;
        size_t row = (size_t)b * HW + q;
        float o = acc[i][j][r] * li[row];
        float xv = bf2f(xbT[row * CIN + c]);
        uT[row * CIN + c] = f2bf(gm * o + xv);
      }
    }
  }
}

// ---------------------------------------------------------------------------
extern "C" void kernel_launch(void* const* d_in, const int* in_sizes, int n_in,
                              void* d_out, int out_size, void* d_ws, size_t ws_size,
                              hipStream_t stream) {
  const float* x     = (const float*)d_in[0];
  const float* Wq    = (const float*)d_in[1];
  const float* bq    = (const float*)d_in[2];
  const float* Wk    = (const float*)d_in[3];
  const float* bk    = (const float*)d_in[4];
  const float* Wv    = (const float*)d_in[5];
  const float* bv    = (const float*)d_in[6];
  const float* gamma = (const float*)d_in[7];
  const float* Wd    = (const float*)d_in[8];
  const float* bd    = (const float*)d_in[9];

  char* ws = (char*)d_ws;
  size_t off = 0;
  auto alloc = [&](size_t bytes) {
    void* p = ws + off;
    off += (bytes + 255) & ~(size_t)255;
    return p;
  };
  u16*   xbT = (u16*)alloc((size_t)16384 * 512 * 2);
  u16*   qkT = (u16*)alloc((size_t)16384 * 128 * 2);
  u16*   vb  = (u16*)alloc((size_t)16384 * 512 * 2);
  u16*   uT  = (u16*)alloc((size_t)16384 * 512 * 2);
  u16*   wqk = (u16*)alloc((size_t)65536 * 2);
  u16*   wvb = (u16*)alloc((size_t)262144 * 2);
  u16*   wdb = (u16*)alloc((size_t)262144 * 2);
  float* bqk = (float*)alloc(128 * 4);
  float* li  = (float*)alloc((size_t)16384 * 4);
  size_t PB = (size_t)HW * HW * 2;
  int nb = 0;
  if      (off + 4 * PB <= ws_size) nb = 4;
  else if (off + 2 * PB <= ws_size) nb = 2;
  else if (off + 1 * PB <= ws_size) nb = 1;
  if (nb == 0) return;  // workspace too small -> poison stays -> loud failure
  u16* Pbuf = (u16*)alloc(nb * PB);

  cast_xT<<<dim3(64, 8, 4), 256, 0, stream>>>(x, xbT);
  cast_w<<<1024, 256, 0, stream>>>(Wq, Wk, Wv, Wd, bq, bk, wqk, wvb, wdb, bqk);
  // qkT (16384,128) = xbT * wqk^T
  gemm_bf16<<<dim3(1, 128), 256, 0, stream>>>(xbT, wqk, bqk, qkT, 16384, 128, 512, 0);
  // v (B,512,HW) = Wv * x
  gemm_bf16<<<dim3(128, 4), 256, 0, stream>>>(wvb, xbT, bv, vb, 512, 16384, 512, 1);
  // attention: P materialize + PV GEMM (staged by batch groups of nb)
  for (int b0 = 0; b0 < 4; b0 += nb) {
    ppass<<<dim3(nb * 64), 512, 0, stream>>>(qkT, Pbuf, li, b0);
    gemm_pv<<<dim3(4, 64, nb), 256, 0, stream>>>(Pbuf, vb, li, xbT, gamma, uT, b0);
  }
  // pam_out (B,512,HW) fp32 = Wd * u
  gemm_bf16<<<dim3(128, 4), 256, 0, stream>>>(wdb, uT, bd, d_out, 512, 16384, 512, 2);
}

// Round 13
// 215.120 us; speedup vs baseline: 1.8520x; 1.0304x over previous
//
#include <hip/hip_runtime.h>
#include <stdint.h>

#define HW   4096
#define CIN  512

typedef __attribute__((ext_vector_type(8))) short short8;
typedef __attribute__((ext_vector_type(4))) float f32x4;
typedef unsigned short u16;

#define GL16(src, ldsdst) __builtin_amdgcn_global_load_lds(                    \
    (const __attribute__((address_space(1))) void*)(src),                      \
    (__attribute__((address_space(3))) void*)(ldsdst), 16, 0, 0)

__device__ __forceinline__ u16 f2bf(float f) {
  union { float f; uint32_t u; } c; c.f = f;
  uint32_t r = (c.u + 0x7FFFu + ((c.u >> 16) & 1u)) >> 16;
  return (u16)r;
}
__device__ __forceinline__ float bf2f(u16 h) {
  union { uint32_t u; float f; } c; c.u = ((uint32_t)h) << 16;
  return c.f;
}

// ---------------------------------------------------------------------------
// x (B,C,HW) fp32  ->  xbT (B*HW, C) bf16   (64x64 tile transpose via LDS)
// ---------------------------------------------------------------------------
__global__ __launch_bounds__(256) void cast_xT(const float* __restrict__ x,
                                               u16* __restrict__ xbT) {
  __shared__ u16 t[64 * 72];
  int p0 = blockIdx.x * 64, c0 = blockIdx.y * 64, b = blockIdx.z;
  int tid = threadIdx.x, r = tid >> 2, ch = tid & 3;
  const float* xp = x + ((size_t)b * CIN + c0 + r) * HW + p0 + ch * 16;
  float4 f0 = *(const float4*)(xp + 0);
  float4 f1 = *(const float4*)(xp + 4);
  float4 f2 = *(const float4*)(xp + 8);
  float4 f3 = *(const float4*)(xp + 12);
  u16* tr = &t[r * 72 + ch * 16];
  tr[0] = f2bf(f0.x); tr[1] = f2bf(f0.y); tr[2] = f2bf(f0.z); tr[3] = f2bf(f0.w);
  tr[4] = f2bf(f1.x); tr[5] = f2bf(f1.y); tr[6] = f2bf(f1.z); tr[7] = f2bf(f1.w);
  tr[8] = f2bf(f2.x); tr[9] = f2bf(f2.y); tr[10] = f2bf(f2.z); tr[11] = f2bf(f2.w);
  tr[12] = f2bf(f3.x); tr[13] = f2bf(f3.y); tr[14] = f2bf(f3.z); tr[15] = f2bf(f3.w);
  __syncthreads();
  u16 o[16];
#pragma unroll
  for (int j = 0; j < 16; j++) o[j] = t[(ch * 16 + j) * 72 + r];
  u16* op = xbT + ((size_t)b * HW + p0 + r) * CIN + c0 + ch * 16;
  *(short8*)(op) = *(short8*)&o[0];
  *(short8*)(op + 8) = *(short8*)&o[8];
}

// ---------------------------------------------------------------------------
// weights -> bf16; wqk = [Wq*log2e; Wk] (128,512); bqk = [bq*log2e; bk]
// ---------------------------------------------------------------------------
__global__ void cast_w(const float* __restrict__ Wq, const float* __restrict__ Wk,
                       const float* __restrict__ Wv, const float* __restrict__ Wd,
                       const float* __restrict__ bq, const float* __restrict__ bk,
                       u16* __restrict__ wqk, u16* __restrict__ wv,
                       u16* __restrict__ wd, float* __restrict__ bqk) {
  const float LOG2E = 1.4426950408889634f;
  int i = blockIdx.x * 256 + threadIdx.x;
  if (i < 65536) wqk[i] = f2bf(i < 32768 ? Wq[i] * LOG2E : Wk[i - 32768]);
  if (i < 262144) { wv[i] = f2bf(Wv[i]); wd[i] = f2bf(Wd[i]); }
  if (i < 128) bqk[i] = (i < 64) ? bq[i] * LOG2E : bk[i - 64];
}

// ---------------------------------------------------------------------------
// Generic GEMM: C(M,N) = A(M,K) * BT(N,K)^T  (both bf16, K-contiguous rows)
// m97-style: 128x128 tile, BK=32, global_load_lds(16B) staging, 4 waves.
// (unchanged - proven R7..R12)
// ---------------------------------------------------------------------------
__global__ __launch_bounds__(256) void gemm_bf16(
    const u16* __restrict__ A, const u16* __restrict__ BT,
    const float* __restrict__ bias, void* __restrict__ out,
    int M, int N, int K, int mode) {
  __shared__ u16 la[128 * 32];
  __shared__ u16 lb[128 * 32];
  int tid = threadIdx.x;
  int w = tid >> 6, lane = tid & 63, m = lane & 15, g = lane >> 4;
  int wm = w >> 1, wn = w & 1;
  int m0 = blockIdx.y * 128, n0 = blockIdx.x * 128;
  int sr = lane >> 2, sc = (lane & 3) * 8;
  const u16* pa0 = A + (size_t)(m0 + w * 32 + sr) * K + sc;
  const u16* pa1 = pa0 + (size_t)16 * K;
  const u16* pb0 = BT + (size_t)(n0 + w * 32 + sr) * K + sc;
  const u16* pb1 = pb0 + (size_t)16 * K;
  u16* la0 = &la[(w * 32) * 32];
  u16* la1 = &la[(w * 32 + 16) * 32];
  u16* lb0 = &lb[(w * 32) * 32];
  u16* lb1 = &lb[(w * 32 + 16) * 32];

  f32x4 acc[4][4];
  f32x4 zero = {0.f, 0.f, 0.f, 0.f};
#pragma unroll
  for (int i = 0; i < 4; i++)
#pragma unroll
    for (int j = 0; j < 4; j++) acc[i][j] = zero;

  for (int k0 = 0; k0 < K; k0 += 32) {
    __syncthreads();
    GL16(pa0 + k0, la0);
    GL16(pa1 + k0, la1);
    GL16(pb0 + k0, lb0);
    GL16(pb1 + k0, lb1);
    __syncthreads();
    short8 af[4], bf[4];
#pragma unroll
    for (int i = 0; i < 4; i++)
      af[i] = *(const short8*)&la[(wm * 64 + i * 16 + m) * 32 + g * 8];
#pragma unroll
    for (int j = 0; j < 4; j++)
      bf[j] = *(const short8*)&lb[(wn * 64 + j * 16 + m) * 32 + g * 8];
#pragma unroll
    for (int i = 0; i < 4; i++)
#pragma unroll
      for (int j = 0; j < 4; j++)
        acc[i][j] = __builtin_amdgcn_mfma_f32_16x16x32_bf16(af[i], bf[j], acc[i][j], 0, 0, 0);
  }

#pragma unroll
  for (int i = 0; i < 4; i++) {
#pragma unroll
    for (int j = 0; j < 4; j++) {
      int row_l = m0 + wm * 64 + i * 16 + g * 4;
      int col = n0 + wn * 64 + j * 16 + m;
#pragma unroll
      for (int r = 0; r < 4; r++) {
        int row = row_l + r;
        float v = acc[i][j][r];
        if (mode == 0) {
          v += bias[col];
          ((u16*)out)[(size_t)row * N + col] = f2bf(v);
        } else {
          v += bias[row];
          size_t addr = ((size_t)(col >> 12) * M + row) * HW + (col & (HW - 1));
          if (mode == 1) ((u16*)out)[addr] = f2bf(v);
          else           ((float*)out)[addr] = v;
        }
      }
    }
  }
}

// ---------------------------------------------------------------------------
// ppass: P = exp2(Q K^T) materialized bf16 + exact row-sum reciprocals.
// (unchanged - proven R7/R10/R11/R12)
// ---------------------------------------------------------------------------
__global__ __launch_bounds__(512) void ppass(
    const u16* __restrict__ qkT, u16* __restrict__ P,
    float* __restrict__ li, int b0) {
  __shared__ u16 kl[256 * 64];
  __shared__ float red[2][64];
  int tid = threadIdx.x;
  int w = tid >> 6, lane = tid & 63, m = lane & 15, g = lane >> 4;
  int blk = blockIdx.x;
  int bb = blk >> 6, b = b0 + bb;
  int q0 = (blk & 63) << 6;
  int qg = w & 3, jh = w >> 2;
  size_t qrow = (size_t)b * HW + q0;

  short8 aq[2];
#pragma unroll
  for (int ks = 0; ks < 2; ks++)
    aq[ks] = *(const short8*)(qkT + (qrow + qg * 16 + m) * 128 + ks * 32 + g * 8);

  float lr[4] = {0.f, 0.f, 0.f, 0.f};
  u16* Pb = P + ((size_t)bb * HW + q0) * HW;
  const u16* kb = qkT + (size_t)b * HW * 128 + 64;
  f32x4 zero = {0.f, 0.f, 0.f, 0.f};

  for (int jp = 0; jp < 16; jp++) {
    int j0 = jp * 256;
    __syncthreads();
#pragma unroll
    for (int it = 0; it < 4; it++) {
      int c = tid + it * 512;
      int row = c >> 3, seg = c & 7;
      short8 v = *(const short8*)(kb + (size_t)(j0 + row) * 128 + seg * 8);
      *(short8*)&kl[row * 64 + ((seg ^ (row & 7)) * 8)] = v;
    }
    __syncthreads();
#pragma unroll
    for (int jt = 0; jt < 8; jt++) {
      int jr = jh * 128 + jt * 16;
      int krow = jr + m;
      f32x4 s = zero;
#pragma unroll
      for (int ks = 0; ks < 2; ks++) {
        short8 bk = *(const short8*)&kl[krow * 64 + (((ks * 4 + g) ^ (krow & 7)) * 8)];
        s = __builtin_amdgcn_mfma_f32_16x16x32_bf16(aq[ks], bk, s, 0, 0, 0);
      }
      int j = j0 + jr + m;
#pragma unroll
      for (int r = 0; r < 4; r++) {
        float p = exp2f(s[r]);
        lr[r] += p;
        Pb[(size_t)(qg * 16 + g * 4 + r) * HW + j] = f2bf(p);
      }
    }
  }
#pragma unroll
  for (int r = 0; r < 4; r++) {
#pragma unroll
    for (int off = 1; off < 16; off <<= 1)
      lr[r] += __shfl_xor(lr[r], off);
  }
  __syncthreads();
  if (m == 0) {
#pragma unroll
    for (int r = 0; r < 4; r++) red[jh][qg * 16 + g * 4 + r] = lr[r];
  }
  __syncthreads();
  if (tid < 64) li[qrow + tid] = 1.0f / (red[0][tid] + red[1][tid]);
}

// ---------------------------------------------------------------------------
// gemm_pv: uT = gamma * (P * V^T) .* li + xbT.
// R13: gemm_bf16's PROVEN 128x128 staging geometry (4 GL16/thread/chunk,
// 4 waves 2x2, wave 64x64 = 4x4 frags -> 0.5 ds_reads/MFMA) + R12's
// K-unroll-2 (stage 2 chunks -> barrier -> compute both -> barrier).
// LDS 32 KB. Grid (4 chan, 32 qtiles, nb) = 512 blocks (2/CU).
// Chunked bijective XCD swizzle: 4 chan-quarters of each 1 MB P-panel
// adjacent -> same XCD -> P fetched ~once from HBM; V L2-resident.
// ---------------------------------------------------------------------------
__global__ __launch_bounds__(256) void gemm_pv(
    const u16* __restrict__ P, const u16* __restrict__ V,
    const float* __restrict__ li, const u16* __restrict__ xbT,
    const float* __restrict__ gamma, u16* __restrict__ uT, int b0) {
  __shared__ u16 la[2][128 * 32];
  __shared__ u16 lb[2][128 * 32];
  int tid = threadIdx.x;
  int w = tid >> 6, lane = tid & 63, m = lane & 15, g = lane >> 4;
  int wm = w >> 1, wn = w & 1;
  // bijective chunk swizzle over linearized grid (total = 128*nb, %8==0)
  int total = gridDim.x * gridDim.y * gridDim.z;
  int lid = blockIdx.x + (blockIdx.y << 2) + (blockIdx.z << 7);
  int wk = (lid & 7) * (total >> 3) + (lid >> 3);
  int chan = (wk & 3) << 7;          // channel quarter: 0,128,256,384
  int q0 = ((wk >> 2) & 31) << 7;    // q-tile of 128
  int bb = wk >> 7, b = b0 + bb;
  int sr = lane >> 2, sc = (lane & 3) * 8;

  const u16* pa0 = P + ((size_t)bb * HW + q0 + w * 32 + sr) * HW + sc;
  const u16* pa1 = pa0 + (size_t)16 * HW;
  const u16* pb0 = V + ((size_t)b * CIN + chan + w * 32 + sr) * HW + sc;
  const u16* pb1 = pb0 + (size_t)16 * HW;

  f32x4 acc[4][4];
  f32x4 zero = {0.f, 0.f, 0.f, 0.f};
#pragma unroll
  for (int i = 0; i < 4; i++)
#pragma unroll
    for (int j = 0; j < 4; j++) acc[i][j] = zero;

  for (int k0 = 0; k0 < HW; k0 += 64) {
    __syncthreads();
#pragma unroll
    for (int c = 0; c < 2; c++) {
      int kk = k0 + c * 32;
      GL16(pa0 + kk, &la[c][(w * 32) * 32]);
      GL16(pa1 + kk, &la[c][(w * 32 + 16) * 32]);
      GL16(pb0 + kk, &lb[c][(w * 32) * 32]);
      GL16(pb1 + kk, &lb[c][(w * 32 + 16) * 32]);
    }
    __syncthreads();
#pragma unroll
    for (int c = 0; c < 2; c++) {
      short8 af[4], bf[4];
#pragma unroll
      for (int i = 0; i < 4; i++)
        af[i] = *(const short8*)&la[c][(wm * 64 + i * 16 + m) * 32 + g * 8];
#pragma unroll
      for (int j = 0; j < 4; j++)
        bf[j] = *(const short8*)&lb[c][(wn * 64 + j * 16 + m) * 32 + g * 8];
#pragma unroll
      for (int i = 0; i < 4; i++)
#pragma unroll
        for (int j = 0; j < 4; j++)
          acc[i][j] = __builtin_amdgcn_mfma_f32_16x16x32_bf16(af[i], bf[j], acc[i][j], 0, 0, 0);
    }
  }

  float gm = gamma[0];
#pragma unroll
  for (int i = 0; i < 4; i++) {
#pragma unroll
    for (int j = 0; j < 4; j++) {
#pragma unroll
      for (int r = 0; r < 4; r++) {
        int q = q0 + wm * 64 + i * 16 + g * 4 + r;
        int c = chan + wn * 64 + j * 16 + m;
        size_t row = (size_t)b * HW + q;
        float o = acc[i][j][r] * li[row];
        float xv = bf2f(xbT[row * CIN + c]);
        uT[row * CIN + c] = f2bf(gm * o + xv);
      }
    }
  }
}

// ---------------------------------------------------------------------------
extern "C" void kernel_launch(void* const* d_in, const int* in_sizes, int n_in,
                              void* d_out, int out_size, void* d_ws, size_t ws_size,
                              hipStream_t stream) {
  const float* x     = (const float*)d_in[0];
  const float* Wq    = (const float*)d_in[1];
  const float* bq    = (const float*)d_in[2];
  const float* Wk    = (const float*)d_in[3];
  const float* bk    = (const float*)d_in[4];
  const float* Wv    = (const float*)d_in[5];
  const float* bv    = (const float*)d_in[6];
  const float* gamma = (const float*)d_in[7];
  const float* Wd    = (const float*)d_in[8];
  const float* bd    = (const float*)d_in[9];

  char* ws = (char*)d_ws;
  size_t off = 0;
  auto alloc = [&](size_t bytes) {
    void* p = ws + off;
    off += (bytes + 255) & ~(size_t)255;
    return p;
  };
  u16*   xbT = (u16*)alloc((size_t)16384 * 512 * 2);
  u16*   qkT = (u16*)alloc((size_t)16384 * 128 * 2);
  u16*   vb  = (u16*)alloc((size_t)16384 * 512 * 2);
  u16*   uT  = (u16*)alloc((size_t)16384 * 512 * 2);
  u16*   wqk = (u16*)alloc((size_t)65536 * 2);
  u16*   wvb = (u16*)alloc((size_t)262144 * 2);
  u16*   wdb = (u16*)alloc((size_t)262144 * 2);
  float* bqk = (float*)alloc(128 * 4);
  float* li  = (float*)alloc((size_t)16384 * 4);
  size_t PB = (size_t)HW * HW * 2;
  int nb = 0;
  if      (off + 4 * PB <= ws_size) nb = 4;
  else if (off + 2 * PB <= ws_size) nb = 2;
  else if (off + 1 * PB <= ws_size) nb = 1;
  if (nb == 0) return;  // workspace too small -> poison stays -> loud failure
  u16* Pbuf = (u16*)alloc(nb * PB);

  cast_xT<<<dim3(64, 8, 4), 256, 0, stream>>>(x, xbT);
  cast_w<<<1024, 256, 0, stream>>>(Wq, Wk, Wv, Wd, bq, bk, wqk, wvb, wdb, bqk);
  // qkT (16384,128) = xbT * wqk^T
  gemm_bf16<<<dim3(1, 128), 256, 0, stream>>>(xbT, wqk, bqk, qkT, 16384, 128, 512, 0);
  // v (B,512,HW) = Wv * x
  gemm_bf16<<<dim3(128, 4), 256, 0, stream>>>(wvb, xbT, bv, vb, 512, 16384, 512, 1);
  // attention: P materialize + PV GEMM (staged by batch groups of nb)
  for (int b0 = 0; b0 < 4; b0 += nb) {
    ppass<<<dim3(nb * 64), 512, 0, stream>>>(qkT, Pbuf, li, b0);
    gemm_pv<<<dim3(4, 32, nb), 256, 0, stream>>>(Pbuf, vb, li, xbT, gamma, uT, b0);
  }
  // pam_out (B,512,HW) fp32 = Wd * u
  gemm_bf16<<<dim3(128, 4), 256, 0, stream>>>(wdb, uT, bd, d_out, 512, 16384, 512, 2);
}